// Round 9
// baseline (243.484 us; speedup 1.0000x reference)
//
#include <hip/hip_runtime.h>
#include <hip/hip_bf16.h>

// B=1024, N(nodes)=128, H=128, D=8
// out = [f_out (B*N)] ++ [g_out (B*N*D)], fp32
//
// R13: two-kernel scheme using d_ws (37.75 MB needed; verbatim-R7 fallback if
// ws_size too small).
//  1) wt_prepass: transpose+convert fp32 weights -> bf16 MFMA-fragment layout
//     wt[i][tt][kk][cs][lane][8], tt=0..15 g-tiles (64 hd-cols each), 16/17 f.
//     Element (col c=cs*16+l15, k=kk*32+quad*8+e) = gw[i][k][tt*64+c] (or fw).
//     Reads 64B-line-coalesced, writes 1KB/wave contiguous. One-time 113 MB
//     HBM traffic (~15-20us).
//  2) sde_main: R7 compute shape (M=512, 512 thr/8 waves, 64 rows/wave, grid
//     256 = 2 row-tiles x 128 nodes, i=bx&127 co-XCD) but NO weight LDS, NO
//     staging, NO loop barriers: per tile 16 coalesced global_load_dwordx4
//     B-fragments (L2/L3-resident), double-buffered bA/bB (static indexing),
//     then the VERBATIM R7 MFMA+ELU body. Waves run free; compiler's counted
//     vmcnt on the prefetch is the only sync. MFMA order identical to R7 ->
//     numerics identical.
// Rationale: R6~R7~R10 (~76us) across occupancy/staging/interleave variants,
// all pipes <50% -- the floor is the staging+barrier convoy itself, so remove
// it from the hot kernel. R8/R9/R12 all died to regalloc spills from enlarged
// monolithic structures; here the hot kernel SHRINKS (~222 live VGPR).
// Spill tripwires: main WRITE_SIZE ~12.3 MB, VGPR <= ~240; prepass WRITE_SIZE
// ~37.7 MB is legitimate output. Mechanism check: SQ_LDS_BANK_CONFLICT ~0.
// A = x*log2e register-resident bf16. Scaled-domain ELU epilogue:
//   elu(t)*w = (max(u,0)*ln2 + exp2(min(u,0)))*w - w,  u = t*log2e
// accumulated without -w; sum(w) subtracted at writeout. Tile seq 16,17,0..15
// (f first; f writeout after 2nd tile), g writeout after the loop.

typedef unsigned short u16;
typedef __attribute__((ext_vector_type(8))) short bf16x8;
typedef __attribute__((ext_vector_type(4))) float f32x4;

#define LOG2E 1.4426950408889634f
#define LN2   0.6931471805599453f

__device__ __forceinline__ uint32_t pk2(float a, float b) {
    union { __hip_bfloat162 h2; uint32_t u; } c;
    c.h2 = __float22bfloat162_rn(make_float2(a, b));
    return c.u;
}
// p += (max(u,0)*ln2 + exp2(min(u,0))) * wv   (elu contribution, missing -wv)
__device__ __forceinline__ float elu_acc(float u, float wv, float p) {
    float m = fmaxf(u, 0.f);
    float e = __builtin_amdgcn_exp2f(fminf(u, 0.f));
    return fmaf(fmaf(m, LN2, e), wv, p);
}

// ---------------- prepass: fp32 weights -> bf16 fragment layout ----------------
__global__ __launch_bounds__(256) void wt_prepass(
    const float* __restrict__ fw, const float* __restrict__ gw, u16* __restrict__ wt)
{
    const int bx = blockIdx.x, t = threadIdx.x;
    const int i    = bx / 72;            // node
    const int rr   = bx % 72;
    const int sub  = t >> 6;
    const int lane = t & 63;
    const int l15  = lane & 15;
    const int quad = lane >> 4;
    const int fni  = rr * 4 + sub;       // 0..287 = tt*16 + (kk*4+cs)
    const int tt   = fni >> 4;
    const int q    = fni & 15;
    const int kk   = q >> 2;
    const int cs   = q & 3;
    const int c    = cs * 16 + l15;
    const int k0   = kk * 32 + quad * 8;

    const float* src; int stride;
    if (tt < 16) { src = gw + (size_t)i * 131072 + (size_t)k0 * 1024 + tt * 64 + c;        stride = 1024; }
    else         { src = fw + (size_t)i * 16384  + (size_t)k0 * 128  + (tt - 16) * 64 + c; stride = 128;  }

    float v[8];
    #pragma unroll
    for (int e = 0; e < 8; ++e) v[e] = src[(size_t)e * stride];

    union { uint32_t u[4]; bf16x8 w; } r;
    r.u[0] = pk2(v[0], v[1]); r.u[1] = pk2(v[2], v[3]);
    r.u[2] = pk2(v[4], v[5]); r.u[3] = pk2(v[6], v[7]);
    *(bf16x8*)(wt + ((size_t)(i * 288 + fni) * 64 + lane) * 8) = r.w;
}

// ---------------- main: barrier-free fragment-direct GEMM + fused ELU ----------------
__global__ __launch_bounds__(512, 2) void sde_main(
    const float* __restrict__ x, const u16* __restrict__ wt,
    const float* __restrict__ Wf, const float* __restrict__ bfp,
    const float* __restrict__ Wg, const float* __restrict__ bgp,
    float* __restrict__ out)
{
    __shared__ float wgs[128];
    __shared__ float wfs[128];

    const int t = threadIdx.x, bx = blockIdx.x;
    const int i    = bx & 127;          // same-node blocks co-XCD (bx%8 == i%8)
    const int b0   = (bx >> 7) << 9;    // 512-row tile base
    const int w    = t >> 6;            // wave 0..7, owns rows w*64..w*64+63
    const int lane = t & 63;
    const int l15  = lane & 15;
    const int quad = lane >> 4;

    if (t < 128) { wgs[t] = Wg[i * 128 + t]; wfs[t] = Wf[i * 128 + t]; }

    // ---- A fragments (verbatim R7): x*log2e -> bf16, rows w*64+rs*16+l15 ----
    bf16x8 afr[4][4];
    #pragma unroll
    for (int rs = 0; rs < 4; ++rs) {
        const float* xr = x + (size_t)(b0 + w * 64 + rs * 16 + l15) * 128 + quad * 8;
        #pragma unroll
        for (int kk = 0; kk < 4; ++kk) {
            float4 v0 = *(const float4*)(xr + kk * 32);
            float4 v1 = *(const float4*)(xr + kk * 32 + 4);
            union { uint32_t u[4]; bf16x8 v; } r;
            r.u[0] = pk2(v0.x * LOG2E, v0.y * LOG2E);
            r.u[1] = pk2(v0.z * LOG2E, v0.w * LOG2E);
            r.u[2] = pk2(v1.x * LOG2E, v1.y * LOG2E);
            r.u[3] = pk2(v1.z * LOG2E, v1.w * LOG2E);
            afr[rs][kk] = r.v;
        }
    }

    __syncthreads();   // wgs/wfs ready (only barrier in the kernel)

    float racc[16];
    #pragma unroll
    for (int qq = 0; qq < 16; ++qq) racc[qq] = 0.f;
    const float bfv = bfp[i], bgv = bgp[i];

    // fragment base for this lane: fragment q of wt-tile tt at wtb + (tt*16+q)*512
    const u16* wtb = wt + (size_t)i * 288 * 512 + (size_t)lane * 8;

    bf16x8 bA[16], bB[16];
    auto load_frags = [&](bf16x8 (&bv)[16], int tt) {
        const u16* p = wtb + (size_t)tt * 16 * 512;
        #pragma unroll
        for (int q = 0; q < 16; ++q) bv[q] = *(const bf16x8*)(p + q * 512);
    };

    // verbatim R7 compute body, B-fragments from registers
    auto compute = [&](const bf16x8 (&bv)[16], bool isF, int ct) {
        float wv[4];
        if (isF) {
            #pragma unroll
            for (int cs = 0; cs < 4; ++cs) wv[cs] = wfs[(ct - 16) * 64 + cs * 16 + l15];
        } else {
            #pragma unroll
            for (int cs = 0; cs < 4; ++cs) wv[cs] = wgs[ct * 8 + cs * 2 + (l15 >> 3)];
        }

        f32x4 acc[4][4];
        #pragma unroll
        for (int rs = 0; rs < 4; ++rs)
            #pragma unroll
            for (int cs = 0; cs < 4; ++cs)
                acc[rs][cs] = (f32x4){0.f, 0.f, 0.f, 0.f};

        #pragma unroll
        for (int kk = 0; kk < 4; ++kk)
            #pragma unroll
            for (int cs = 0; cs < 4; ++cs)
                #pragma unroll
                for (int rs = 0; rs < 4; ++rs)
                    acc[rs][cs] = __builtin_amdgcn_mfma_f32_16x16x32_bf16(afr[rs][kk], bv[kk * 4 + cs], acc[rs][cs], 0, 0, 0);

        // fused epilogue; C/D layout col=l15, row=quad*4+rg
        #pragma unroll
        for (int rs = 0; rs < 4; ++rs)
            #pragma unroll
            for (int rg = 0; rg < 4; ++rg) {
                float s = racc[rs * 4 + rg];
                s = elu_acc(acc[rs][0][rg], wv[0], s);
                s = elu_acc(acc[rs][1][rg], wv[1], s);
                s = elu_acc(acc[rs][2][rg], wv[2], s);
                s = elu_acc(acc[rs][3][rg], wv[3], s);
                racc[rs * 4 + rg] = s;
            }
    };

    // tile seq: idx 0->tt16 (f), 1->tt17 (f), idx>=2 -> tt idx-2 (g)
    load_frags(bA, 16);
    for (int it = 0; it < 9; ++it) {
        const int iA = 2 * it, iB = 2 * it + 1;
        const int ttB = (iB < 2) ? 16 + iB : iB - 2;

        load_frags(bB, ttB);                        // prefetch; bA use waits vmcnt(16)
        compute(bA, iA < 2, (iA < 2) ? 16 + iA : iA - 2);

        if (it < 8) load_frags(bA, iA);             // next even tile: tt = (iA+2)-2 = iA
        compute(bB, iB < 2, ttB);

        if (it == 0) {
            // f complete (tt16,17): subtract per-lane sum(wf), 16-lane reduce, store, reset
            float Sf = 0.f;
            #pragma unroll
            for (int jh = 0; jh < 8; ++jh) Sf += wfs[jh * 16 + l15];
            #pragma unroll
            for (int rs = 0; rs < 4; ++rs)
                #pragma unroll
                for (int rg = 0; rg < 4; ++rg) {
                    float f = racc[rs * 4 + rg] - Sf;
                    f += __shfl_xor(f, 1);
                    f += __shfl_xor(f, 2);
                    f += __shfl_xor(f, 4);
                    f += __shfl_xor(f, 8);
                    if (l15 == 0) {
                        const int row = w * 64 + rs * 16 + quad * 4 + rg;
                        out[(size_t)(b0 + row) * 128 + i] = f + bfv;
                    }
                    racc[rs * 4 + rg] = 0.f;
                }
        }
    }

    // ---- g writeout (verbatim R7): subtract per-lane sum(wg), pair-reduce, store ----
    float Sg = 0.f;
    {
        const int hb = l15 >> 3;
        #pragma unroll 8
        for (int h = 0; h < 128; h += 2) Sg += wgs[h + hb];
    }
    #pragma unroll
    for (int rs = 0; rs < 4; ++rs)
        #pragma unroll
        for (int rg = 0; rg < 4; ++rg) {
            float g = racc[rs * 4 + rg] - Sg;
            g += __shfl_xor(g, 8);             // combine h-parity halves (same d = l15&7)
            if (l15 < 8) {
                const int row = w * 64 + rs * 16 + quad * 4 + rg;
                out[(size_t)131072 + ((size_t)(b0 + row) * 128 + i) * 8 + (lane & 7)] = g + bgv;
            }
        }
}

// ---------------- fallback: verbatim R7 (76us) if ws_size too small ----------------
__global__ __launch_bounds__(512, 2) void sde_fused_r7(
    const float* __restrict__ x, const float* __restrict__ fw, const float* __restrict__ gw,
    const float* __restrict__ Wf, const float* __restrict__ bfp,
    const float* __restrict__ Wg, const float* __restrict__ bgp,
    float* __restrict__ out)
{
    __shared__ u16 wst[2][64 * 128];
    __shared__ float wgs[128];
    __shared__ float wfs[128];

    const int t = threadIdx.x, bx = blockIdx.x;
    const int i    = bx & 127;
    const int b0   = (bx >> 7) << 9;
    const int w    = t >> 6;
    const int lane = t & 63;
    const int l15  = lane & 15;
    const int quad = lane >> 4;
    const int l31  = lane & 31;
    const int jj   = lane >> 5;
    const int c0   = l31 * 2;
    const int sw   = (l15 >> 1) & 7;
    const int j    = w * 2 + jj;

    if (t < 128) { wgs[t] = Wg[i * 128 + t]; wfs[t] = Wf[i * 128 + t]; }

    const float* gwi = gw + (size_t)i * 131072;
    const float* fwi = fw + (size_t)i * 16384;

    float2 vr[8];
    auto load_tile = [&](int ct) {
        const float* src; int rstride;
        if (ct < 16) { src = gwi + ct * 64;        rstride = 1024; }
        else         { src = fwi + (ct - 16) * 64; rstride = 128;  }
        const float* s2 = src + (size_t)(8 * j) * rstride + c0;
        #pragma unroll
        for (int r = 0; r < 8; ++r) vr[r] = *(const float2*)(s2 + (size_t)r * rstride);
    };
    auto write_tile = [&](int p) {
        const int slot = (j ^ (l31 & 7)) << 3;
        union { uint32_t u[4]; bf16x8 v; } rr;
        rr.u[0] = pk2(vr[0].x, vr[1].x); rr.u[1] = pk2(vr[2].x, vr[3].x);
        rr.u[2] = pk2(vr[4].x, vr[5].x); rr.u[3] = pk2(vr[6].x, vr[7].x);
        *(bf16x8*)&wst[p][c0 * 128 + slot] = rr.v;
        rr.u[0] = pk2(vr[0].y, vr[1].y); rr.u[1] = pk2(vr[2].y, vr[3].y);
        rr.u[2] = pk2(vr[4].y, vr[5].y); rr.u[3] = pk2(vr[6].y, vr[7].y);
        *(bf16x8*)&wst[p][(c0 + 1) * 128 + slot] = rr.v;
    };

    load_tile(16);

    bf16x8 afr[4][4];
    #pragma unroll
    for (int rs = 0; rs < 4; ++rs) {
        const float* xr = x + (size_t)(b0 + w * 64 + rs * 16 + l15) * 128 + quad * 8;
        #pragma unroll
        for (int kk = 0; kk < 4; ++kk) {
            float4 v0 = *(const float4*)(xr + kk * 32);
            float4 v1 = *(const float4*)(xr + kk * 32 + 4);
            union { uint32_t u[4]; bf16x8 v; } r;
            r.u[0] = pk2(v0.x * LOG2E, v0.y * LOG2E);
            r.u[1] = pk2(v0.z * LOG2E, v0.w * LOG2E);
            r.u[2] = pk2(v1.x * LOG2E, v1.y * LOG2E);
            r.u[3] = pk2(v1.z * LOG2E, v1.w * LOG2E);
            afr[rs][kk] = r.v;
        }
    }

    write_tile(0);
    __syncthreads();

    float racc[16];
    #pragma unroll
    for (int q = 0; q < 16; ++q) racc[q] = 0.f;
    const float bfv = bfp[i], bgv = bgp[i];

    int p = 0;
    for (int idx = 0; idx < 18; ++idx) {
        const int ct  = (idx < 2) ? 16 + idx : idx - 2;
        const bool pre = idx < 17;
        const int ctn = (idx == 0) ? 17 : idx - 1;

        f32x4 acc[4][4];
        #pragma unroll
        for (int rs = 0; rs < 4; ++rs)
            #pragma unroll
            for (int cs = 0; cs < 4; ++cs)
                acc[rs][cs] = (f32x4){0.f, 0.f, 0.f, 0.f};

        if (pre) load_tile(ctn);

        #pragma unroll
        for (int kk = 0; kk < 4; ++kk) {
            const int co = ((kk * 4 + quad) ^ sw) << 3;
            bf16x8 bv[4];
            #pragma unroll
            for (int cs = 0; cs < 4; ++cs)
                bv[cs] = *(const bf16x8*)&wst[p][(cs * 16 + l15) * 128 + co];
            #pragma unroll
            for (int cs = 0; cs < 4; ++cs)
                #pragma unroll
                for (int rs = 0; rs < 4; ++rs)
                    acc[rs][cs] = __builtin_amdgcn_mfma_f32_16x16x32_bf16(afr[rs][kk], bv[cs], acc[rs][cs], 0, 0, 0);
        }

        float wv[4];
        if (idx < 2) {
            #pragma unroll
            for (int cs = 0; cs < 4; ++cs) wv[cs] = wfs[(ct - 16) * 64 + cs * 16 + l15];
        } else {
            #pragma unroll
            for (int cs = 0; cs < 4; ++cs) wv[cs] = wgs[ct * 8 + cs * 2 + (l15 >> 3)];
        }
        #pragma unroll
        for (int rs = 0; rs < 4; ++rs)
            #pragma unroll
            for (int rg = 0; rg < 4; ++rg) {
                float s = racc[rs * 4 + rg];
                s = elu_acc(acc[rs][0][rg], wv[0], s);
                s = elu_acc(acc[rs][1][rg], wv[1], s);
                s = elu_acc(acc[rs][2][rg], wv[2], s);
                s = elu_acc(acc[rs][3][rg], wv[3], s);
                racc[rs * 4 + rg] = s;
            }

        if (pre) write_tile(p ^ 1);

        if (idx == 1) {
            float Sf = 0.f;
            #pragma unroll
            for (int jh = 0; jh < 8; ++jh) Sf += wfs[jh * 16 + l15];
            #pragma unroll
            for (int rs = 0; rs < 4; ++rs)
                #pragma unroll
                for (int rg = 0; rg < 4; ++rg) {
                    float f = racc[rs * 4 + rg] - Sf;
                    f += __shfl_xor(f, 1);
                    f += __shfl_xor(f, 2);
                    f += __shfl_xor(f, 4);
                    f += __shfl_xor(f, 8);
                    if (l15 == 0) {
                        const int row = w * 64 + rs * 16 + quad * 4 + rg;
                        out[(size_t)(b0 + row) * 128 + i] = f + bfv;
                    }
                    racc[rs * 4 + rg] = 0.f;
                }
        }

        if (pre) __syncthreads();
        p ^= 1;
    }

    float Sg = 0.f;
    {
        const int hb = l15 >> 3;
        #pragma unroll 8
        for (int h = 0; h < 128; h += 2) Sg += wgs[h + hb];
    }
    #pragma unroll
    for (int rs = 0; rs < 4; ++rs)
        #pragma unroll
        for (int rg = 0; rg < 4; ++rg) {
            float g = racc[rs * 4 + rg] - Sg;
            g += __shfl_xor(g, 8);
            if (l15 < 8) {
                const int row = w * 64 + rs * 16 + quad * 4 + rg;
                out[(size_t)131072 + ((size_t)(b0 + row) * 128 + i) * 8 + (lane & 7)] = g + bgv;
            }
        }
}

extern "C" void kernel_launch(void* const* d_in, const int* in_sizes, int n_in,
                              void* d_out, int out_size, void* d_ws, size_t ws_size,
                              hipStream_t stream) {
    const float* x  = (const float*)d_in[0];
    const float* fw = (const float*)d_in[1];
    const float* gw = (const float*)d_in[2];
    const float* Wf = (const float*)d_in[3];
    const float* bf = (const float*)d_in[4];
    const float* Wg = (const float*)d_in[5];
    const float* bg = (const float*)d_in[6];
    float* out = (float*)d_out;

    const size_t WT_BYTES = (size_t)128 * 288 * 64 * 16;   // 37,748,736
    if (d_ws != nullptr && ws_size >= WT_BYTES) {
        u16* wt = (u16*)d_ws;
        wt_prepass<<<9216, 256, 0, stream>>>(fw, gw, wt);
        sde_main<<<256, 512, 0, stream>>>(x, wt, Wf, bf, Wg, bg, out);
    } else {
        sde_fused_r7<<<256, 512, 0, stream>>>(x, fw, gw, Wf, bf, Wg, bg, out);
    }
}

// Round 10
// 183.959 us; speedup vs baseline: 1.3236x; 1.3236x over previous
//
#include <hip/hip_runtime.h>
#include <hip/hip_bf16.h>

// B=1024, N(nodes)=128, H=128, D=8
// out = [f_out (B*N)] ++ [g_out (B*N*D)], fp32
//
// R14: R13's two-kernel scheme (verified correct in R13; perf killed by spill)
// with a REGISTER-BUDGETED main kernel.
//  1) wt_prepass (verbatim R13): fp32 weights -> bf16 MFMA-fragment layout
//     wt[i][tt][kk][cs][lane][8]; tt 0..15 g-tiles (64 hd cols), 16/17 f.
//     One-time 113 MB HBM (~15-20us).
//  2) sde_main: R7 compute shape (M=512, 512thr/8 waves, 64 rows/wave, grid
//     256 = 2 row-tiles x 128 nodes, i=bx&127 co-XCD), NO weight LDS, NO
//     staging, NO loop barriers. Per tile: SINGLE bv[16] fragment buffer
//     (64 VGPR): wait loads -> 64 MFMA (consume bv) -> issue next tile's 16
//     loads (WAR; issues as soon as MFMAs have read bv) -> ELU epilogue
//     (~600cyc VALU on acc) covers the L2 latency of the prefetch.
//     Live set ~215 regs (bv 64 + afr 64 + acc 64 + racc 16 + misc) <= 256
//     cap at 2 waves/SIMD. R13's bA+bB double buffer (280 regs) spilled
//     281 MB; this is the one structural change.
// Spill tripwire (decisive): main WRITE_SIZE ~4-6 MB, no 128 VGPR cap.
// Mechanism check: SQ_LDS_BANK_CONFLICT == 0.
// A = x*log2e register-resident bf16. Scaled-domain ELU epilogue:
//   elu(t)*w = (max(u,0)*ln2 + exp2(min(u,0)))*w - w,  u = t*log2e
// accumulated without -w; sum(w) subtracted at writeout. Tile seq 16,17,0..15
// (f first; f writeout after idx==1), g writeout after the loop. MFMA order
// identical to R7/R13 -> numerics identical (absmax 0.015625).
// Fallback: verbatim R7 (76us) if ws_size < 37.75 MB.

typedef unsigned short u16;
typedef __attribute__((ext_vector_type(8))) short bf16x8;
typedef __attribute__((ext_vector_type(4))) float f32x4;

#define LOG2E 1.4426950408889634f
#define LN2   0.6931471805599453f

__device__ __forceinline__ uint32_t pk2(float a, float b) {
    union { __hip_bfloat162 h2; uint32_t u; } c;
    c.h2 = __float22bfloat162_rn(make_float2(a, b));
    return c.u;
}
// p += (max(u,0)*ln2 + exp2(min(u,0))) * wv   (elu contribution, missing -wv)
__device__ __forceinline__ float elu_acc(float u, float wv, float p) {
    float m = fmaxf(u, 0.f);
    float e = __builtin_amdgcn_exp2f(fminf(u, 0.f));
    return fmaf(fmaf(m, LN2, e), wv, p);
}

// ---------------- prepass (verbatim R13): fp32 weights -> bf16 fragment layout ----------------
__global__ __launch_bounds__(256) void wt_prepass(
    const float* __restrict__ fw, const float* __restrict__ gw, u16* __restrict__ wt)
{
    const int bx = blockIdx.x, t = threadIdx.x;
    const int i    = bx / 72;            // node
    const int rr   = bx % 72;
    const int sub  = t >> 6;
    const int lane = t & 63;
    const int l15  = lane & 15;
    const int quad = lane >> 4;
    const int fni  = rr * 4 + sub;       // 0..287 = tt*16 + (kk*4+cs)
    const int tt   = fni >> 4;
    const int q    = fni & 15;
    const int kk   = q >> 2;
    const int cs   = q & 3;
    const int c    = cs * 16 + l15;
    const int k0   = kk * 32 + quad * 8;

    const float* src; int stride;
    if (tt < 16) { src = gw + (size_t)i * 131072 + (size_t)k0 * 1024 + tt * 64 + c;        stride = 1024; }
    else         { src = fw + (size_t)i * 16384  + (size_t)k0 * 128  + (tt - 16) * 64 + c; stride = 128;  }

    float v[8];
    #pragma unroll
    for (int e = 0; e < 8; ++e) v[e] = src[(size_t)e * stride];

    union { uint32_t u[4]; bf16x8 w; } r;
    r.u[0] = pk2(v[0], v[1]); r.u[1] = pk2(v[2], v[3]);
    r.u[2] = pk2(v[4], v[5]); r.u[3] = pk2(v[6], v[7]);
    *(bf16x8*)(wt + ((size_t)(i * 288 + fni) * 64 + lane) * 8) = r.w;
}

// ---------------- main: barrier-free fragment-direct GEMM + fused ELU ----------------
__global__ __launch_bounds__(512, 2) void sde_main(
    const float* __restrict__ x, const u16* __restrict__ wt,
    const float* __restrict__ Wf, const float* __restrict__ bfp,
    const float* __restrict__ Wg, const float* __restrict__ bgp,
    float* __restrict__ out)
{
    __shared__ float wgs[128];
    __shared__ float wfs[128];

    const int t = threadIdx.x, bx = blockIdx.x;
    const int i    = bx & 127;          // same-node blocks co-XCD (bx%8 == i%8)
    const int b0   = (bx >> 7) << 9;    // 512-row tile base
    const int w    = t >> 6;            // wave 0..7, owns rows w*64..w*64+63
    const int lane = t & 63;
    const int l15  = lane & 15;
    const int quad = lane >> 4;

    if (t < 128) { wgs[t] = Wg[i * 128 + t]; wfs[t] = Wf[i * 128 + t]; }

    // ---- A fragments (verbatim R7): x*log2e -> bf16, rows w*64+rs*16+l15 ----
    bf16x8 afr[4][4];
    #pragma unroll
    for (int rs = 0; rs < 4; ++rs) {
        const float* xr = x + (size_t)(b0 + w * 64 + rs * 16 + l15) * 128 + quad * 8;
        #pragma unroll
        for (int kk = 0; kk < 4; ++kk) {
            float4 v0 = *(const float4*)(xr + kk * 32);
            float4 v1 = *(const float4*)(xr + kk * 32 + 4);
            union { uint32_t u[4]; bf16x8 v; } r;
            r.u[0] = pk2(v0.x * LOG2E, v0.y * LOG2E);
            r.u[1] = pk2(v0.z * LOG2E, v0.w * LOG2E);
            r.u[2] = pk2(v1.x * LOG2E, v1.y * LOG2E);
            r.u[3] = pk2(v1.z * LOG2E, v1.w * LOG2E);
            afr[rs][kk] = r.v;
        }
    }

    __syncthreads();   // wgs/wfs ready (only barrier in the kernel)

    float racc[16];
    #pragma unroll
    for (int qq = 0; qq < 16; ++qq) racc[qq] = 0.f;
    const float bfv = bfp[i], bgv = bgp[i];

    // fragment base for this lane: fragment q of wt-tile tt at wtb + (tt*16+q)*512
    const u16* wtb = wt + (size_t)i * 288 * 512 + (size_t)lane * 8;

    bf16x8 bv[16];                      // SINGLE buffer (64 VGPR)
    auto load_frags = [&](int tt) {
        const u16* p = wtb + (size_t)tt * 16 * 512;
        #pragma unroll
        for (int q = 0; q < 16; ++q) bv[q] = *(const bf16x8*)(p + q * 512);
    };

    load_frags(16);                     // prologue: first tile's fragments in flight

    for (int idx = 0; idx < 18; ++idx) {
        const int ct = (idx < 2) ? 16 + idx : idx - 2;

        f32x4 acc[4][4];
        #pragma unroll
        for (int rs = 0; rs < 4; ++rs)
            #pragma unroll
            for (int cs = 0; cs < 4; ++cs)
                acc[rs][cs] = (f32x4){0.f, 0.f, 0.f, 0.f};

        // consume bv (waits vmcnt for in-flight loads); order identical to R7
        #pragma unroll
        for (int kk = 0; kk < 4; ++kk)
            #pragma unroll
            for (int cs = 0; cs < 4; ++cs)
                #pragma unroll
                for (int rs = 0; rs < 4; ++rs)
                    acc[rs][cs] = __builtin_amdgcn_mfma_f32_16x16x32_bf16(afr[rs][kk], bv[kk * 4 + cs], acc[rs][cs], 0, 0, 0);

        // prefetch next tile into bv (WAR: issues after MFMAs read bv);
        // the epilogue below covers the L2 latency.
        if (idx < 17) load_frags((idx + 1 < 2) ? 17 : idx - 1);

        // fused epilogue; C/D layout col=l15, row=quad*4+rg
        float wv[4];
        if (idx < 2) {
            #pragma unroll
            for (int cs = 0; cs < 4; ++cs) wv[cs] = wfs[(ct - 16) * 64 + cs * 16 + l15];
        } else {
            #pragma unroll
            for (int cs = 0; cs < 4; ++cs) wv[cs] = wgs[ct * 8 + cs * 2 + (l15 >> 3)];
        }
        #pragma unroll
        for (int rs = 0; rs < 4; ++rs)
            #pragma unroll
            for (int rg = 0; rg < 4; ++rg) {
                float s = racc[rs * 4 + rg];
                s = elu_acc(acc[rs][0][rg], wv[0], s);
                s = elu_acc(acc[rs][1][rg], wv[1], s);
                s = elu_acc(acc[rs][2][rg], wv[2], s);
                s = elu_acc(acc[rs][3][rg], wv[3], s);
                racc[rs * 4 + rg] = s;
            }

        if (idx == 1) {
            // f complete (tiles 16,17): subtract per-lane sum(wf), 16-lane reduce, store, reset
            float Sf = 0.f;
            #pragma unroll
            for (int jh = 0; jh < 8; ++jh) Sf += wfs[jh * 16 + l15];
            #pragma unroll
            for (int rs = 0; rs < 4; ++rs)
                #pragma unroll
                for (int rg = 0; rg < 4; ++rg) {
                    float f = racc[rs * 4 + rg] - Sf;
                    f += __shfl_xor(f, 1);
                    f += __shfl_xor(f, 2);
                    f += __shfl_xor(f, 4);
                    f += __shfl_xor(f, 8);
                    if (l15 == 0) {
                        const int row = w * 64 + rs * 16 + quad * 4 + rg;
                        out[(size_t)(b0 + row) * 128 + i] = f + bfv;
                    }
                    racc[rs * 4 + rg] = 0.f;
                }
        }
    }

    // ---- g writeout (verbatim R7): subtract per-lane sum(wg), pair-reduce, store ----
    float Sg = 0.f;
    {
        const int hb = l15 >> 3;
        #pragma unroll 8
        for (int h = 0; h < 128; h += 2) Sg += wgs[h + hb];
    }
    #pragma unroll
    for (int rs = 0; rs < 4; ++rs)
        #pragma unroll
        for (int rg = 0; rg < 4; ++rg) {
            float g = racc[rs * 4 + rg] - Sg;
            g += __shfl_xor(g, 8);             // combine h-parity halves (same d = l15&7)
            if (l15 < 8) {
                const int row = w * 64 + rs * 16 + quad * 4 + rg;
                out[(size_t)131072 + ((size_t)(b0 + row) * 128 + i) * 8 + (lane & 7)] = g + bgv;
            }
        }
}

// ---------------- fallback: verbatim R7 (76us) if ws_size too small ----------------
__global__ __launch_bounds__(512, 2) void sde_fused_r7(
    const float* __restrict__ x, const float* __restrict__ fw, const float* __restrict__ gw,
    const float* __restrict__ Wf, const float* __restrict__ bfp,
    const float* __restrict__ Wg, const float* __restrict__ bgp,
    float* __restrict__ out)
{
    __shared__ u16 wst[2][64 * 128];
    __shared__ float wgs[128];
    __shared__ float wfs[128];

    const int t = threadIdx.x, bx = blockIdx.x;
    const int i    = bx & 127;
    const int b0   = (bx >> 7) << 9;
    const int w    = t >> 6;
    const int lane = t & 63;
    const int l15  = lane & 15;
    const int quad = lane >> 4;
    const int l31  = lane & 31;
    const int jj   = lane >> 5;
    const int c0   = l31 * 2;
    const int sw   = (l15 >> 1) & 7;
    const int j    = w * 2 + jj;

    if (t < 128) { wgs[t] = Wg[i * 128 + t]; wfs[t] = Wf[i * 128 + t]; }

    const float* gwi = gw + (size_t)i * 131072;
    const float* fwi = fw + (size_t)i * 16384;

    float2 vr[8];
    auto load_tile = [&](int ct) {
        const float* src; int rstride;
        if (ct < 16) { src = gwi + ct * 64;        rstride = 1024; }
        else         { src = fwi + (ct - 16) * 64; rstride = 128;  }
        const float* s2 = src + (size_t)(8 * j) * rstride + c0;
        #pragma unroll
        for (int r = 0; r < 8; ++r) vr[r] = *(const float2*)(s2 + (size_t)r * rstride);
    };
    auto write_tile = [&](int p) {
        const int slot = (j ^ (l31 & 7)) << 3;
        union { uint32_t u[4]; bf16x8 v; } rr;
        rr.u[0] = pk2(vr[0].x, vr[1].x); rr.u[1] = pk2(vr[2].x, vr[3].x);
        rr.u[2] = pk2(vr[4].x, vr[5].x); rr.u[3] = pk2(vr[6].x, vr[7].x);
        *(bf16x8*)&wst[p][c0 * 128 + slot] = rr.v;
        rr.u[0] = pk2(vr[0].y, vr[1].y); rr.u[1] = pk2(vr[2].y, vr[3].y);
        rr.u[2] = pk2(vr[4].y, vr[5].y); rr.u[3] = pk2(vr[6].y, vr[7].y);
        *(bf16x8*)&wst[p][(c0 + 1) * 128 + slot] = rr.v;
    };

    load_tile(16);

    bf16x8 afr[4][4];
    #pragma unroll
    for (int rs = 0; rs < 4; ++rs) {
        const float* xr = x + (size_t)(b0 + w * 64 + rs * 16 + l15) * 128 + quad * 8;
        #pragma unroll
        for (int kk = 0; kk < 4; ++kk) {
            float4 v0 = *(const float4*)(xr + kk * 32);
            float4 v1 = *(const float4*)(xr + kk * 32 + 4);
            union { uint32_t u[4]; bf16x8 v; } r;
            r.u[0] = pk2(v0.x * LOG2E, v0.y * LOG2E);
            r.u[1] = pk2(v0.z * LOG2E, v0.w * LOG2E);
            r.u[2] = pk2(v1.x * LOG2E, v1.y * LOG2E);
            r.u[3] = pk2(v1.z * LOG2E, v1.w * LOG2E);
            afr[rs][kk] = r.v;
        }
    }

    write_tile(0);
    __syncthreads();

    float racc[16];
    #pragma unroll
    for (int q = 0; q < 16; ++q) racc[q] = 0.f;
    const float bfv = bfp[i], bgv = bgp[i];

    int p = 0;
    for (int idx = 0; idx < 18; ++idx) {
        const int ct  = (idx < 2) ? 16 + idx : idx - 2;
        const bool pre = idx < 17;
        const int ctn = (idx == 0) ? 17 : idx - 1;

        f32x4 acc[4][4];
        #pragma unroll
        for (int rs = 0; rs < 4; ++rs)
            #pragma unroll
            for (int cs = 0; cs < 4; ++cs)
                acc[rs][cs] = (f32x4){0.f, 0.f, 0.f, 0.f};

        if (pre) load_tile(ctn);

        #pragma unroll
        for (int kk = 0; kk < 4; ++kk) {
            const int co = ((kk * 4 + quad) ^ sw) << 3;
            bf16x8 bv[4];
            #pragma unroll
            for (int cs = 0; cs < 4; ++cs)
                bv[cs] = *(const bf16x8*)&wst[p][(cs * 16 + l15) * 128 + co];
            #pragma unroll
            for (int cs = 0; cs < 4; ++cs)
                #pragma unroll
                for (int rs = 0; rs < 4; ++rs)
                    acc[rs][cs] = __builtin_amdgcn_mfma_f32_16x16x32_bf16(afr[rs][kk], bv[cs], acc[rs][cs], 0, 0, 0);
        }

        float wv[4];
        if (idx < 2) {
            #pragma unroll
            for (int cs = 0; cs < 4; ++cs) wv[cs] = wfs[(ct - 16) * 64 + cs * 16 + l15];
        } else {
            #pragma unroll
            for (int cs = 0; cs < 4; ++cs) wv[cs] = wgs[ct * 8 + cs * 2 + (l15 >> 3)];
        }
        #pragma unroll
        for (int rs = 0; rs < 4; ++rs)
            #pragma unroll
            for (int rg = 0; rg < 4; ++rg) {
                float s = racc[rs * 4 + rg];
                s = elu_acc(acc[rs][0][rg], wv[0], s);
                s = elu_acc(acc[rs][1][rg], wv[1], s);
                s = elu_acc(acc[rs][2][rg], wv[2], s);
                s = elu_acc(acc[rs][3][rg], wv[3], s);
                racc[rs * 4 + rg] = s;
            }

        if (pre) write_tile(p ^ 1);

        if (idx == 1) {
            float Sf = 0.f;
            #pragma unroll
            for (int jh = 0; jh < 8; ++jh) Sf += wfs[jh * 16 + l15];
            #pragma unroll
            for (int rs = 0; rs < 4; ++rs)
                #pragma unroll
                for (int rg = 0; rg < 4; ++rg) {
                    float f = racc[rs * 4 + rg] - Sf;
                    f += __shfl_xor(f, 1);
                    f += __shfl_xor(f, 2);
                    f += __shfl_xor(f, 4);
                    f += __shfl_xor(f, 8);
                    if (l15 == 0) {
                        const int row = w * 64 + rs * 16 + quad * 4 + rg;
                        out[(size_t)(b0 + row) * 128 + i] = f + bfv;
                    }
                    racc[rs * 4 + rg] = 0.f;
                }
        }

        if (pre) __syncthreads();
        p ^= 1;
    }

    float Sg = 0.f;
    {
        const int hb = l15 >> 3;
        #pragma unroll 8
        for (int h = 0; h < 128; h += 2) Sg += wgs[h + hb];
    }
    #pragma unroll
    for (int rs = 0; rs < 4; ++rs)
        #pragma unroll
        for (int rg = 0; rg < 4; ++rg) {
            float g = racc[rs * 4 + rg] - Sg;
            g += __shfl_xor(g, 8);
            if (l15 < 8) {
                const int row = w * 64 + rs * 16 + quad * 4 + rg;
                out[(size_t)131072 + ((size_t)(b0 + row) * 128 + i) * 8 + (lane & 7)] = g + bgv;
            }
        }
}

extern "C" void kernel_launch(void* const* d_in, const int* in_sizes, int n_in,
                              void* d_out, int out_size, void* d_ws, size_t ws_size,
                              hipStream_t stream) {
    const float* x  = (const float*)d_in[0];
    const float* fw = (const float*)d_in[1];
    const float* gw = (const float*)d_in[2];
    const float* Wf = (const float*)d_in[3];
    const float* bf = (const float*)d_in[4];
    const float* Wg = (const float*)d_in[5];
    const float* bg = (const float*)d_in[6];
    float* out = (float*)d_out;

    const size_t WT_BYTES = (size_t)128 * 288 * 64 * 16;   // 37,748,736
    if (d_ws != nullptr && ws_size >= WT_BYTES) {
        u16* wt = (u16*)d_ws;
        wt_prepass<<<9216, 256, 0, stream>>>(fw, gw, wt);
        sde_main<<<256, 512, 0, stream>>>(x, wt, Wf, bf, Wg, bg, out);
    } else {
        sde_fused_r7<<<256, 512, 0, stream>>>(x, fw, gw, Wf, bf, Wg, bg, out);
    }
}